// Round 15
// baseline (810.010 us; speedup 1.0000x reference)
//
#include <hip/hip_runtime.h>
#include <hip/hip_bf16.h>
#include <stdint.h>

#define EN    8
#define DIN   512
#define HID   1024
#define BATCH 16384
#define LN_EPS 1e-5f

typedef __bf16   bf16x8 __attribute__((ext_vector_type(8)));
typedef float    f32x4  __attribute__((ext_vector_type(4)));
typedef uint16_t u16x8  __attribute__((ext_vector_type(8)));
typedef uint16_t u16x4  __attribute__((ext_vector_type(4)));
typedef float    fl4    __attribute__((ext_vector_type(4)));

__device__ __forceinline__ uint16_t f2bf(float f) {
  uint32_t x = __builtin_bit_cast(uint32_t, f);
  uint32_t r = (x + 0x7fffu + ((x >> 16) & 1u)) >> 16;  // RNE
  return (uint16_t)r;
}
__device__ __forceinline__ float bf2f(uint16_t u) {
  return __builtin_bit_cast(float, (uint32_t)u << 16);
}

__device__ __forceinline__ void gload16(const uint16_t* g, char* lds_d) {
  __builtin_amdgcn_global_load_lds(
      (const __attribute__((address_space(1))) uint32_t*)g,
      (__attribute__((address_space(3))) uint32_t*)lds_d, 16, 0, 0);
}

__device__ __forceinline__ f32x4 MF(bf16x8 a, bf16x8 b, f32x4 c) {
  return __builtin_amdgcn_mfma_f32_16x16x32_bf16(a, b, c, 0, 0, 0);
}

#define SB0() __builtin_amdgcn_sched_barrier(0)

// ---------------- conversion: fp32 -> bf16 ----------------
__global__ __launch_bounds__(256) void cvt_bf16(const float* __restrict__ src,
                                                uint16_t* __restrict__ dst, long n) {
  long i = ((long)blockIdx.x * 256 + threadIdx.x) * 4;
  if (i >= n) return;
  fl4 v = *(const fl4*)(src + i);
  u16x4 o;
  #pragma unroll
  for (int j = 0; j < 4; ++j) o[j] = f2bf(v[j]);
  *(u16x4*)(dst + i) = o;
}

// ---------------- transpose + convert: [E][R][C] fp32 -> [E][C][R] bf16 ----------------
__global__ __launch_bounds__(256) void transpose_cvt(const float* __restrict__ src,
                                                     uint16_t* __restrict__ dst,
                                                     int R, int C) {
  __shared__ float tile[32][33];
  const int e = blockIdx.z;
  const int c0 = blockIdx.x * 32;
  const int r0 = blockIdx.y * 32;
  const int tx = threadIdx.x & 31, ty = threadIdx.x >> 5;
  const float* s = src + (size_t)e * R * C;
  uint16_t*    d = dst + (size_t)e * R * C;
  #pragma unroll
  for (int i = 0; i < 32; i += 8)
    tile[ty + i][tx] = s[(size_t)(r0 + ty + i) * C + (c0 + tx)];
  __syncthreads();
  #pragma unroll
  for (int i = 0; i < 32; i += 8)
    d[(size_t)(c0 + ty + i) * R + (r0 + tx)] = f2bf(tile[tx][ty + i]);
}

// ====== stage 1 GEMM: R14 gemm4w + per-row LN-stats partials (two-phase LN) ======
// C[e][M][HID] = A[e][M][K]*Bt^T + bias (bias folded into acc; h1 stores pre-LN
// values, SAME as R14).  Extra epilogue: Spart[nt][e][M] (sum, sumsq) partials
// over this block's 256 cols.  Everything else verbatim R14 (659.6us baseline).
__global__ __launch_bounds__(256, 1) void gemm4w_s1(
    const uint16_t* __restrict__ A,
    const uint16_t* __restrict__ Bt,
    const float*    __restrict__ bias,
    uint16_t*       __restrict__ C,
    float2*         __restrict__ Spart,
    int M, int K) {
  __shared__ __attribute__((aligned(16))) char lds[131072];
  const int tid = threadIdx.x;
  const int bx  = blockIdx.x;
  const int e   = bx & 7;
  const int t   = bx >> 3;
  const int mt  = t >> 2;
  const int nt  = t & 3;
  const int NT  = K >> 6;

  const uint16_t* Ae = A + (size_t)(mt * 256) * K;      // A chunk-local (no estride)
  const uint16_t* Be = Bt + ((size_t)e * HID + nt * 256) * K;

  const int l  = tid & 63, wid = tid >> 6;
  const int wr = wid >> 1, wc = wid & 1;
  const int fr = l & 15, kq = l >> 4, f7 = fr & 7;

  const int r8 = l >> 3;
  const int su = (l & 7) ^ r8;
  const uint16_t* pA = Ae + (size_t)(wid * 8 + r8) * K + su * 8;
  const uint16_t* pB = Be + (size_t)(wid * 8 + r8) * K + su * 8;
  char* const dst0 = lds + tid * 16;

  const int rdA0 = (wr * 128 + fr) * 128 + ((kq ^ f7) << 4);
  const int rdB0 = 32768 + (wc * 128 + fr) * 128 + ((kq ^ f7) << 4);

  f32x4 acc[8][8];
  #pragma unroll
  for (int i = 0; i < 8; ++i)
    #pragma unroll
    for (int j = 0; j < 8; ++j) acc[i][j] = (f32x4)0.0f;

  auto STAGE = [&](int kt) {
    char* db = dst0 + ((kt & 1) << 16);
    const uint16_t* sa = pA + kt * 64;
    const uint16_t* sb = pB + kt * 64;
    #pragma unroll
    for (int j = 0; j < 8; ++j) gload16(sa + (size_t)(j * 32) * K, db + j * 4096);
    #pragma unroll
    for (int j = 0; j < 8; ++j) gload16(sb + (size_t)(j * 32) * K, db + 32768 + j * 4096);
  };

  STAGE(0);
  asm volatile("s_waitcnt vmcnt(0)");
  SB0();
  __builtin_amdgcn_s_barrier();
  SB0();

  bf16x8 a0[8], b0[8], a1[8], b1[8];
  {
    const char* rb = lds;
    #pragma unroll
    for (int i = 0; i < 8; ++i) {
      a0[i] = *(const bf16x8*)(rb + rdA0 + i * 2048);
      b0[i] = *(const bf16x8*)(rb + rdB0 + i * 2048);
    }
  }

  for (int kt = 0; kt < NT; ++kt) {
    const char* rb = lds + ((kt & 1) << 16);
    const char* rq = lds + (((kt + 1) & 1) << 16);
    if (kt + 1 < NT) STAGE(kt + 1);
    #pragma unroll
    for (int mi = 0; mi < 8; ++mi) {
      a1[mi] = *(const bf16x8*)(rb + ((rdA0 + mi * 2048) ^ 64));
      b1[mi] = *(const bf16x8*)(rb + ((rdB0 + mi * 2048) ^ 64));
      __builtin_amdgcn_s_setprio(1);
      #pragma unroll
      for (int ni = 0; ni < 8; ++ni)
        acc[mi][ni] = MF(a0[mi], b0[ni], acc[mi][ni]);
      __builtin_amdgcn_s_setprio(0);
    }
    #pragma unroll
    for (int mi = 0; mi < 8; ++mi) {
      __builtin_amdgcn_s_setprio(1);
      #pragma unroll
      for (int ni = 0; ni < 8; ++ni)
        acc[mi][ni] = MF(a1[mi], b1[ni], acc[mi][ni]);
      __builtin_amdgcn_s_setprio(0);
    }
    if (kt + 1 < NT) {
      asm volatile("s_waitcnt vmcnt(0)");
      SB0();
      __builtin_amdgcn_s_barrier();
      SB0();
      #pragma unroll
      for (int i = 0; i < 8; ++i) {
        a0[i] = *(const bf16x8*)(rq + rdA0 + i * 2048);
        b0[i] = *(const bf16x8*)(rq + rdB0 + i * 2048);
      }
    }
  }

  // bias folded into acc (needed for stats), then store h1 (pre-LN, as R14)
  const int col0 = nt * 256 + wc * 128 + fr;
  const int row0 = mt * 256 + wr * 128 + kq * 4;
  #pragma unroll
  for (int ni = 0; ni < 8; ++ni) {
    const float bv = bias[(size_t)e * HID + col0 + ni * 16];
    #pragma unroll
    for (int mi = 0; mi < 8; ++mi)
      #pragma unroll
      for (int i = 0; i < 4; ++i) acc[mi][ni][i] += bv;
  }
  #pragma unroll
  for (int mi = 0; mi < 8; ++mi) {
    #pragma unroll
    for (int i = 0; i < 4; ++i) {
      const int rg = row0 + mi * 16 + i;
      uint16_t* cp = C + ((size_t)e * M + rg) * HID + col0;
      #pragma unroll
      for (int ni = 0; ni < 8; ++ni)
        cp[ni * 16] = f2bf(acc[mi][ni][i]);
    }
  }

  // ---- LN-stats partials over this block's 256 cols ----
  __syncthreads();                          // all LDS frag reads done; reuse LDS
  float2* red = (float2*)lds;               // [2 wr][2 wc][128 rows]
  #pragma unroll
  for (int mi = 0; mi < 8; ++mi)
    #pragma unroll
    for (int i = 0; i < 4; ++i) {
      float s = 0.f, q = 0.f;
      #pragma unroll
      for (int ni = 0; ni < 8; ++ni) { const float v = acc[mi][ni][i]; s += v; q += v * v; }
      #pragma unroll
      for (int m = 1; m < 16; m <<= 1) { s += __shfl_xor(s, m); q += __shfl_xor(q, m); }
      if (fr == 0) red[(wr * 2 + wc) * 128 + mi * 16 + kq * 4 + i] = make_float2(s, q);
    }
  __syncthreads();
  if (tid < 256) {
    const int rl = tid, wrx = rl >> 7, rr = rl & 127;
    const float2 p0 = red[(wrx * 2 + 0) * 128 + rr];
    const float2 p1 = red[(wrx * 2 + 1) * 128 + rr];
    Spart[((size_t)nt * EN + e) * M + mt * 256 + rl] =
        make_float2(p0.x + p1.x, p0.y + p1.y);
  }
}

// ---------------- stats: [4][EN*M] partials -> [EN*M] (mu, rs) ----------------
__global__ __launch_bounds__(256) void stats_reduce(const float2* __restrict__ S,
                                                    float2* __restrict__ st,
                                                    long n) {     // n = EN*M
  const long i = (long)blockIdx.x * 256 + threadIdx.x;
  if (i >= n) return;
  float s = 0.f, q = 0.f;
  #pragma unroll
  for (int p = 0; p < 4; ++p) {
    const float2 v = S[(size_t)p * n + i];
    s += v.x; q += v.y;
  }
  const float mu = s * (1.f / HID);
  const float vr = q * (1.f / HID) - mu * mu;
  st[i] = make_float2(mu, rsqrtf(vr + LN_EPS));
}

// ====== stage 2 GEMM: R14 structure; A reg-staged with fused LN+ReLU apply ======
// A = pre-LN h1 (bf16) + per-row stats -> normalized bf16 written to the SAME LDS
// bytes the DMA wrote in R14 (frag-read path identical).  B staging/epilogue
// verbatim R14.  Unfenced MFMA body (R11: neutral) so the apply-VALU interleaves.
__global__ __launch_bounds__(256, 1) void gemm4w_s2(
    const uint16_t* __restrict__ A,       // h1 [E][M][K=HID], pre-LN
    const float2*   __restrict__ st,      // [E][M] (mu, rs)
    const float*    __restrict__ g,       // [E][HID]
    const float*    __restrict__ be,      // [E][HID]
    const uint16_t* __restrict__ Bt,
    const float*    __restrict__ bias,
    uint16_t*       __restrict__ C,
    int M, int K) {
  __shared__ __attribute__((aligned(16))) char lds[131072];
  const int tid = threadIdx.x;
  const int bx  = blockIdx.x;
  const int e   = bx & 7;
  const int t   = bx >> 3;
  const int mt  = t >> 2;
  const int nt  = t & 3;
  const int NT  = K >> 6;

  const uint16_t* Ae = A + (size_t)e * M * K + (size_t)(mt * 256) * K;
  const uint16_t* Be = Bt + ((size_t)e * HID + nt * 256) * K;

  const int l  = tid & 63, wid = tid >> 6;
  const int wr = wid >> 1, wc = wid & 1;
  const int fr = l & 15, kq = l >> 4, f7 = fr & 7;

  const int r8 = l >> 3;
  const int su = (l & 7) ^ r8;
  const int rbase = wid * 8 + r8;                      // staged rows: rbase + j*32
  const uint16_t* pA = Ae + (size_t)rbase * K + su * 8;
  const uint16_t* pB = Be + (size_t)rbase * K + su * 8;
  char* const dst0 = lds + tid * 16;

  // kt-invariant per-row stats for this thread's 8 staged rows
  float mu8[8], rs8[8];
  {
    const float2* sb = st + (size_t)e * M + mt * 256 + rbase;
    #pragma unroll
    for (int j = 0; j < 8; ++j) { const float2 v = sb[j * 32]; mu8[j] = v.x; rs8[j] = v.y; }
  }
  const float* gcol = g  + (size_t)e * HID + su * 8;   // + kt*64
  const float* ecol = be + (size_t)e * HID + su * 8;

  const int rdA0 = (wr * 128 + fr) * 128 + ((kq ^ f7) << 4);
  const int rdB0 = 32768 + (wc * 128 + fr) * 128 + ((kq ^ f7) << 4);

  f32x4 acc[8][8];
  #pragma unroll
  for (int i = 0; i < 8; ++i)
    #pragma unroll
    for (int j = 0; j < 8; ++j) acc[i][j] = (f32x4)0.0f;

  auto STAGE_B = [&](int kt) {
    char* db = dst0 + ((kt & 1) << 16);
    const uint16_t* sb = pB + kt * 64;
    #pragma unroll
    for (int j = 0; j < 8; ++j) gload16(sb + (size_t)(j * 32) * K, db + 32768 + j * 4096);
  };
  u16x8 aw[8];
  auto LOAD_A = [&](int kt) {
    const uint16_t* sa = pA + kt * 64;
    #pragma unroll
    for (int j = 0; j < 8; ++j) aw[j] = *(const u16x8*)(sa + (size_t)(j * 32) * K);
  };
  auto APPLY_WRITE = [&](int kt) {
    char* db = dst0 + ((kt & 1) << 16);
    float gk[8], bk[8];
    const float* gp = gcol + kt * 64;
    const float* ep = ecol + kt * 64;
    *(fl4*)&gk[0] = *(const fl4*)gp;  *(fl4*)&gk[4] = *(const fl4*)(gp + 4);
    *(fl4*)&bk[0] = *(const fl4*)ep;  *(fl4*)&bk[4] = *(const fl4*)(ep + 4);
    #pragma unroll
    for (int j = 0; j < 8; ++j) {
      u16x8 o;
      #pragma unroll
      for (int x = 0; x < 8; ++x) {
        const float v = (bf2f(aw[j][x]) - mu8[j]) * rs8[j] * gk[x] + bk[x];
        o[x] = f2bf(fmaxf(v, 0.f));
      }
      *(u16x8*)(db + j * 4096) = o;
    }
  };

  // prologue
  STAGE_B(0);
  LOAD_A(0);
  APPLY_WRITE(0);
  __syncthreads();

  bf16x8 a0[8], b0[8], a1[8], b1[8];
  {
    const char* rb = lds;
    #pragma unroll
    for (int i = 0; i < 8; ++i) {
      a0[i] = *(const bf16x8*)(rb + rdA0 + i * 2048);
      b0[i] = *(const bf16x8*)(rb + rdB0 + i * 2048);
    }
  }

  for (int kt = 0; kt < NT; ++kt) {
    const char* rb = lds + ((kt & 1) << 16);
    const char* rq = lds + (((kt + 1) & 1) << 16);
    if (kt + 1 < NT) { STAGE_B(kt + 1); LOAD_A(kt + 1); }
    #pragma unroll
    for (int mi = 0; mi < 8; ++mi) {
      a1[mi] = *(const bf16x8*)(rb + ((rdA0 + mi * 2048) ^ 64));
      b1[mi] = *(const bf16x8*)(rb + ((rdB0 + mi * 2048) ^ 64));
      #pragma unroll
      for (int ni = 0; ni < 8; ++ni)
        acc[mi][ni] = MF(a0[mi], b0[ni], acc[mi][ni]);
    }
    #pragma unroll
    for (int mi = 0; mi < 8; ++mi)
      #pragma unroll
      for (int ni = 0; ni < 8; ++ni)
        acc[mi][ni] = MF(a1[mi], b1[ni], acc[mi][ni]);
    if (kt + 1 < NT) {
      APPLY_WRITE(kt + 1);                 // LN-apply + ds_write next A buf
      __syncthreads();                     // drains vmcnt (B DMA) + lgkm (writes)
      #pragma unroll
      for (int i = 0; i < 8; ++i) {
        a0[i] = *(const bf16x8*)(rq + rdA0 + i * 2048);
        b0[i] = *(const bf16x8*)(rq + rdB0 + i * 2048);
      }
    }
  }

  const int col0 = nt * 256 + wc * 128 + fr;
  const int row0 = mt * 256 + wr * 128 + kq * 4;
  float bv[8];
  #pragma unroll
  for (int ni = 0; ni < 8; ++ni) bv[ni] = bias[(size_t)e * HID + col0 + ni * 16];
  #pragma unroll
  for (int mi = 0; mi < 8; ++mi) {
    #pragma unroll
    for (int i = 0; i < 4; ++i) {
      const int rg = row0 + mi * 16 + i;
      uint16_t* cp = C + ((size_t)e * M + rg) * HID + col0;
      #pragma unroll
      for (int ni = 0; ni < 8; ++ni)
        cp[ni * 16] = f2bf(acc[mi][ni][i] + bv[ni]);
    }
  }
}

// ------- fused LN2 + ReLU + head dot + min: reads pre-LN h2, writes q/qs only -------
__global__ __launch_bounds__(256) void ln_head(const uint16_t* __restrict__ h,
                                               const float* __restrict__ g,
                                               const float* __restrict__ be,
                                               const float* __restrict__ W3,
                                               const float* __restrict__ b3,
                                               float* __restrict__ out,
                                               int b0, int CB) {
  __shared__ float qsh[EN];
  const int wv = threadIdx.x >> 6, l = threadIdx.x & 63;
  const long b = blockIdx.x;
  #pragma unroll
  for (int ee = 0; ee < 2; ++ee) {
    const int e = wv + ee * 4;
    const uint16_t* p = h + ((size_t)e * CB + b) * HID;
    u16x8 s0 = *(const u16x8*)(p + l * 8);
    u16x8 s1 = *(const u16x8*)(p + 512 + l * 8);
    float v[16];
    #pragma unroll
    for (int j = 0; j < 8; ++j) { v[j] = bf2f(s0[j]); v[8 + j] = bf2f(s1[j]); }
    float sum = 0.f, sq = 0.f;
    #pragma unroll
    for (int j = 0; j < 16; ++j) { sum += v[j]; sq += v[j] * v[j]; }
    #pragma unroll
    for (int m = 1; m < 64; m <<= 1) {
      sum += __shfl_xor(sum, m);
      sq  += __shfl_xor(sq, m);
    }
    const float mu  = sum * (1.0f / HID);
    const float var = sq * (1.0f / HID) - mu * mu;
    const float rs  = rsqrtf(var + LN_EPS);
    const float* gp = g  + (size_t)e * HID;
    const float* bp = be + (size_t)e * HID;
    const float* w  = W3 + (size_t)e * HID;
    float dot = 0.f;
    #pragma unroll
    for (int j = 0; j < 8; ++j) {
      const int c0 = l * 8 + j, c1 = 512 + l * 8 + j;
      float x0 = fmaxf((v[j]     - mu) * rs * gp[c0] + bp[c0], 0.f);
      float x1 = fmaxf((v[8 + j] - mu) * rs * gp[c1] + bp[c1], 0.f);
      dot += x0 * w[c0] + x1 * w[c1];
    }
    #pragma unroll
    for (int m = 1; m < 64; m <<= 1) dot += __shfl_xor(dot, m);
    if (l == 0) {
      const float qe = dot + b3[e];
      qsh[e] = qe;
      out[BATCH + (size_t)e * BATCH + b0 + b] = qe;   // qs
    }
  }
  __syncthreads();
  if (threadIdx.x == 0) {
    float m = qsh[0];
    #pragma unroll
    for (int i = 1; i < EN; ++i) m = fminf(m, qsh[i]);
    out[b0 + b] = m;                                   // q
  }
}

extern "C" void kernel_launch(void* const* d_in, const int* in_sizes, int n_in,
                              void* d_out, int out_size, void* d_ws, size_t ws_size,
                              hipStream_t stream) {
  const float* x   = (const float*)d_in[0];
  const float* W1  = (const float*)d_in[1];
  const float* b1  = (const float*)d_in[2];
  const float* g1  = (const float*)d_in[3];
  const float* be1 = (const float*)d_in[4];
  const float* W2  = (const float*)d_in[5];
  const float* b2  = (const float*)d_in[6];
  const float* g2  = (const float*)d_in[7];
  const float* be2 = (const float*)d_in[8];
  const float* W3  = (const float*)d_in[9];
  const float* b3  = (const float*)d_in[10];
  float* out = (float*)d_out;

  // ---- fixed workspace region: converted inputs (40 MB) ----
  char* ws = (char*)d_ws;
  uint16_t* xb  = (uint16_t*)ws; ws += (size_t)BATCH * DIN * 2;      // 16 MB
  uint16_t* w1t = (uint16_t*)ws; ws += (size_t)EN * DIN * HID * 2;   // 8 MB
  uint16_t* w2t = (uint16_t*)ws; ws += (size_t)EN * HID * HID * 2;   // 16 MB
  size_t fixed = (size_t)(ws - (char*)d_ws);

  // ---- chunk size: h1 + h2 + Spart(4x) + stats per row ----
  size_t avail = (ws_size > fixed) ? (ws_size - fixed) : 0;
  const size_t per_row = 2ULL * EN * HID * 2ULL      // h1 + h2
                       + 4ULL * EN * 8ULL            // Spart (float2)
                       + (size_t)EN * 8ULL;          // stats (float2)
  int CB = BATCH;
  while (CB > 256 && (size_t)CB * per_row > avail) CB >>= 1;
  const int nchunks = BATCH / CB;

  uint16_t* h1   = (uint16_t*)ws; ws += (size_t)EN * CB * HID * 2;
  uint16_t* h2   = (uint16_t*)ws; ws += (size_t)EN * CB * HID * 2;
  float2*   Sp   = (float2*)ws;   ws += 4ULL * EN * CB * 8;
  float2*   stat = (float2*)ws;

  // ---- one-time conversions ----
  cvt_bf16<<<(BATCH * DIN / 4 + 255) / 256, 256, 0, stream>>>(x, xb, (long)BATCH * DIN);
  transpose_cvt<<<dim3(HID / 32, DIN / 32, EN), 256, 0, stream>>>(W1, w1t, DIN, HID);
  transpose_cvt<<<dim3(HID / 32, HID / 32, EN), 256, 0, stream>>>(W2, w2t, HID, HID);

  const int gblocks = (CB / 256) * (HID / 256) * EN;
  const long nst = (long)EN * CB;

  for (int c = 0; c < nchunks; ++c) {
    const int b0 = c * CB;
    gemm4w_s1<<<gblocks, 256, 0, stream>>>(xb + (size_t)b0 * DIN, w1t, b1, h1,
                                           Sp, CB, DIN);
    stats_reduce<<<(int)((nst + 255) / 256), 256, 0, stream>>>(Sp, stat, nst);
    gemm4w_s2<<<gblocks, 256, 0, stream>>>(h1, stat, g1, be1, w2t, b2, h2,
                                           CB, HID);
    ln_head<<<CB, 256, 0, stream>>>(h2, g2, be2, W3, b3, out, b0, CB);
  }
}

// Round 16
// 671.581 us; speedup vs baseline: 1.2061x; 1.2061x over previous
//
#include <hip/hip_runtime.h>
#include <hip/hip_bf16.h>
#include <stdint.h>

#define EN    8
#define DIN   512
#define HID   1024
#define BATCH 16384
#define LN_EPS 1e-5f

typedef __bf16   bf16x8 __attribute__((ext_vector_type(8)));
typedef float    f32x16 __attribute__((ext_vector_type(16)));
typedef uint16_t u16x8  __attribute__((ext_vector_type(8)));
typedef uint16_t u16x4  __attribute__((ext_vector_type(4)));
typedef float    fl4    __attribute__((ext_vector_type(4)));

__device__ __forceinline__ uint16_t f2bf(float f) {
  uint32_t x = __builtin_bit_cast(uint32_t, f);
  uint32_t r = (x + 0x7fffu + ((x >> 16) & 1u)) >> 16;  // RNE
  return (uint16_t)r;
}
__device__ __forceinline__ float bf2f(uint16_t u) {
  return __builtin_bit_cast(float, (uint32_t)u << 16);
}

__device__ __forceinline__ void gload16(const uint16_t* g, char* lds_d) {
  __builtin_amdgcn_global_load_lds(
      (const __attribute__((address_space(1))) uint32_t*)g,
      (__attribute__((address_space(3))) uint32_t*)lds_d, 16, 0, 0);
}

__device__ __forceinline__ f32x16 MF32(bf16x8 a, bf16x8 b, f32x16 c) {
  return __builtin_amdgcn_mfma_f32_32x32x16_bf16(a, b, c, 0, 0, 0);
}

#define SB0() __builtin_amdgcn_sched_barrier(0)

// ---------------- conversion: fp32 -> bf16 ----------------
__global__ __launch_bounds__(256) void cvt_bf16(const float* __restrict__ src,
                                                uint16_t* __restrict__ dst, long n) {
  long i = ((long)blockIdx.x * 256 + threadIdx.x) * 4;
  if (i >= n) return;
  fl4 v = *(const fl4*)(src + i);
  u16x4 o;
  #pragma unroll
  for (int j = 0; j < 4; ++j) o[j] = f2bf(v[j]);
  *(u16x4*)(dst + i) = o;
}

// ---------------- transpose + convert: [E][R][C] fp32 -> [E][C][R] bf16 ----------------
__global__ __launch_bounds__(256) void transpose_cvt(const float* __restrict__ src,
                                                     uint16_t* __restrict__ dst,
                                                     int R, int C) {
  __shared__ float tile[32][33];
  const int e = blockIdx.z;
  const int c0 = blockIdx.x * 32;
  const int r0 = blockIdx.y * 32;
  const int tx = threadIdx.x & 31, ty = threadIdx.x >> 5;
  const float* s = src + (size_t)e * R * C;
  uint16_t*    d = dst + (size_t)e * R * C;
  #pragma unroll
  for (int i = 0; i < 32; i += 8)
    tile[ty + i][tx] = s[(size_t)(r0 + ty + i) * C + (c0 + tx)];
  __syncthreads();
  #pragma unroll
  for (int i = 0; i < 32; i += 8)
    d[(size_t)(c0 + ty + i) * R + (r0 + tx)] = f2bf(tile[tx][ty + i]);
}

// ====== 256x256 GEMM — R14 structure, MFMA shape 32x32x16 (half the instructions) ======
// C[e][M][HID] = A[e][M][K] * Bt[e][HID][K]^T + bias.  256 thr = 4 waves (2M x 2N),
// wave tile 128x128 = 4x4 tiles of 32x32; BK=64 = 4 K-steps of 16.
// Staging/LDS/swizzle/sync verbatim R14 (659.6us baseline).  A/B frag: lane l ->
// row/col l&31, k = (l>>5)*8 + j (16x16 convention extended).  C/D [m74/m101]:
// col=l&31, row=(reg&3)+8*(reg>>2)+4*(l>>5).  64 MFMA/kt/wave (was 128), same
// 32 b128 LDS reads -> probes whether the ~5800cyc/kt wall is per-instruction.
__global__ __launch_bounds__(256, 1) void gemm4w(
    const uint16_t* __restrict__ A, size_t a_estride,
    const uint16_t* __restrict__ Bt,
    const float*    __restrict__ bias,
    uint16_t*       __restrict__ C,
    int M, int K) {
  __shared__ __attribute__((aligned(16))) char lds[131072];
  const int tid = threadIdx.x;
  const int bx  = blockIdx.x;
  const int e   = bx & 7;            // member -> XCD pinning
  const int t   = bx >> 3;
  const int mt  = t >> 2;            // nt inner: neighbors share A panel
  const int nt  = t & 3;
  const int NT  = K >> 6;            // K-tiles of 64

  const uint16_t* Ae = A + (size_t)e * a_estride + (size_t)(mt * 256) * K;
  const uint16_t* Be = Bt + ((size_t)e * HID + nt * 256) * K;

  const int l  = tid & 63, wid = tid >> 6;
  const int wr = wid >> 1, wc = wid & 1;        // 2 x 2 waves, tile 128x128
  const int l5 = l >> 5;                        // k-half within frag

  // staging: lane covers row (wid*8 + l>>3) (+j*32), phys unit l&7, logical su
  const int r8 = l >> 3;
  const int su = (l & 7) ^ r8;
  const uint16_t* pA = Ae + (size_t)(wid * 8 + r8) * K + su * 8;
  const uint16_t* pB = Be + (size_t)(wid * 8 + r8) * K + su * 8;
  char* const dst0 = lds + tid * 16;

  // frag read bases: row = (wave_off + l&31), unit u = ks*2 + l5, phys = u ^ (row&7)
  // addr(mi,ks) = (rdA0 + mi*4096) ^ ((ks&1)<<5) ^ ((ks>>1)<<6)    [row&7 == l&7]
  const int rdA0 = (wr * 128 + (l & 31)) * 128 + ((l5 ^ (l & 7)) << 4);
  const int rdB0 = 32768 + (wc * 128 + (l & 31)) * 128 + ((l5 ^ (l & 7)) << 4);

  f32x16 acc[4][4];
  #pragma unroll
  for (int i = 0; i < 4; ++i)
    #pragma unroll
    for (int j = 0; j < 4; ++j) acc[i][j] = (f32x16)0.0f;

  auto STAGE = [&](int kt) {
    char* db = dst0 + ((kt & 1) << 16);
    const uint16_t* sa = pA + kt * 64;
    const uint16_t* sb = pB + kt * 64;
    #pragma unroll
    for (int j = 0; j < 8; ++j) gload16(sa + (size_t)(j * 32) * K, db + j * 4096);
    #pragma unroll
    for (int j = 0; j < 8; ++j) gload16(sb + (size_t)(j * 32) * K, db + 32768 + j * 4096);
  };

  // prologue
  STAGE(0);
  asm volatile("s_waitcnt vmcnt(0)");
  SB0();
  __builtin_amdgcn_s_barrier();
  SB0();

  // frag arrays: [mi*2 + kk], kk = ks&1; kh0 = ks{0,1}, kh1 = ks{2,3} (^64)
  bf16x8 a0[8], b0[8], a1[8], b1[8];
  {
    const char* rb = lds;
    #pragma unroll
    for (int mi = 0; mi < 4; ++mi)
      #pragma unroll
      for (int kk = 0; kk < 2; ++kk) {
        a0[mi * 2 + kk] = *(const bf16x8*)(rb + ((rdA0 + mi * 4096) ^ (kk << 5)));
        b0[mi * 2 + kk] = *(const bf16x8*)(rb + ((rdB0 + mi * 4096) ^ (kk << 5)));
      }
  }

  for (int kt = 0; kt < NT; ++kt) {
    const char* rb = lds + ((kt & 1) << 16);
    const char* rq = lds + (((kt + 1) & 1) << 16);
    if (kt + 1 < NT) STAGE(kt + 1);            // 16 gload_lds, lands during this kt
    // ---- kh0: 32 MFMA; kh1 frag reads issued ahead of each burst ----
    #pragma unroll
    for (int mi = 0; mi < 4; ++mi) {
      #pragma unroll
      for (int kk = 0; kk < 2; ++kk) {
        a1[mi * 2 + kk] = *(const bf16x8*)(rb + ((rdA0 + mi * 4096) ^ 64 ^ (kk << 5)));
        b1[mi * 2 + kk] = *(const bf16x8*)(rb + ((rdB0 + mi * 4096) ^ 64 ^ (kk << 5)));
      }
      __builtin_amdgcn_s_setprio(1);
      #pragma unroll
      for (int ni = 0; ni < 4; ++ni)
        #pragma unroll
        for (int kk = 0; kk < 2; ++kk)
          acc[mi][ni] = MF32(a0[mi * 2 + kk], b0[ni * 2 + kk], acc[mi][ni]);
      __builtin_amdgcn_s_setprio(0);
    }
    // ---- kh1: 32 MFMA ----
    #pragma unroll
    for (int mi = 0; mi < 4; ++mi) {
      __builtin_amdgcn_s_setprio(1);
      #pragma unroll
      for (int ni = 0; ni < 4; ++ni)
        #pragma unroll
        for (int kk = 0; kk < 2; ++kk)
          acc[mi][ni] = MF32(a1[mi * 2 + kk], b1[ni * 2 + kk], acc[mi][ni]);
      __builtin_amdgcn_s_setprio(0);
    }
    if (kt + 1 < NT) {
      asm volatile("s_waitcnt vmcnt(0)");       // stage(kt+1) landed
      SB0();
      __builtin_amdgcn_s_barrier();
      SB0();
      #pragma unroll
      for (int mi = 0; mi < 4; ++mi)
        #pragma unroll
        for (int kk = 0; kk < 2; ++kk) {
          a0[mi * 2 + kk] = *(const bf16x8*)(rq + ((rdA0 + mi * 4096) ^ (kk << 5)));
          b0[mi * 2 + kk] = *(const bf16x8*)(rq + ((rdB0 + mi * 4096) ^ (kk << 5)));
        }
    }
  }

  // epilogue: bias + bf16 store.  D map [m74/m101]: col=l&31, row=(reg&3)+8*(reg>>2)+4*(l>>5)
  const int col0 = nt * 256 + wc * 128 + (l & 31);
  const int row0 = mt * 256 + wr * 128 + 4 * l5;
  float bv[4];
  #pragma unroll
  for (int ni = 0; ni < 4; ++ni) bv[ni] = bias[(size_t)e * HID + col0 + ni * 32];
  #pragma unroll
  for (int mi = 0; mi < 4; ++mi) {
    #pragma unroll
    for (int reg = 0; reg < 16; ++reg) {
      const int rg = row0 + mi * 32 + (reg & 3) + 8 * (reg >> 2);
      uint16_t* cp = C + ((size_t)e * M + rg) * HID + col0;
      #pragma unroll
      for (int ni = 0; ni < 4; ++ni)
        cp[ni * 32] = f2bf(acc[mi][ni][reg] + bv[ni]);
    }
  }
}

// ---------------- LayerNorm + ReLU, in place on bf16 [E*CB][HID] ----------------
__global__ __launch_bounds__(256) void ln_relu(uint16_t* __restrict__ h,
                                               const float* __restrict__ g,
                                               const float* __restrict__ be,
                                               int kshift) {        // e = row >> kshift
  const int wid = threadIdx.x >> 6, l = threadIdx.x & 63;
  const long row = (long)blockIdx.x * 4 + wid;
  const int e = (int)(row >> kshift);
  uint16_t* p = h + row * HID;

  u16x8 s0 = *(const u16x8*)(p + l * 8);
  u16x8 s1 = *(const u16x8*)(p + 512 + l * 8);
  float v[16];
  #pragma unroll
  for (int j = 0; j < 8; ++j) { v[j] = bf2f(s0[j]); v[8 + j] = bf2f(s1[j]); }

  float sum = 0.f, sq = 0.f;
  #pragma unroll
  for (int j = 0; j < 16; ++j) { sum += v[j]; sq += v[j] * v[j]; }
  #pragma unroll
  for (int m = 1; m < 64; m <<= 1) {
    sum += __shfl_xor(sum, m);
    sq  += __shfl_xor(sq, m);
  }
  const float mu  = sum * (1.0f / HID);
  const float var = sq * (1.0f / HID) - mu * mu;
  const float rs  = rsqrtf(var + LN_EPS);

  const float* gp = g  + (size_t)e * HID;
  const float* bp = be + (size_t)e * HID;
  u16x8 o0, o1;
  #pragma unroll
  for (int j = 0; j < 8; ++j) {
    const int c0 = l * 8 + j, c1 = 512 + l * 8 + j;
    float x0 = (v[j]     - mu) * rs * gp[c0] + bp[c0];
    float x1 = (v[8 + j] - mu) * rs * gp[c1] + bp[c1];
    o0[j] = f2bf(fmaxf(x0, 0.f));
    o1[j] = f2bf(fmaxf(x1, 0.f));
  }
  *(u16x8*)(p + l * 8) = o0;
  *(u16x8*)(p + 512 + l * 8) = o1;
}

// ------- fused LN2 + ReLU + head dot + min: reads pre-LN h2, writes q/qs only -------
__global__ __launch_bounds__(256) void ln_head(const uint16_t* __restrict__ h,
                                               const float* __restrict__ g,
                                               const float* __restrict__ be,
                                               const float* __restrict__ W3,
                                               const float* __restrict__ b3,
                                               float* __restrict__ out,
                                               int b0, int CB) {
  __shared__ float qsh[EN];
  const int wv = threadIdx.x >> 6, l = threadIdx.x & 63;
  const long b = blockIdx.x;
  #pragma unroll
  for (int ee = 0; ee < 2; ++ee) {
    const int e = wv + ee * 4;
    const uint16_t* p = h + ((size_t)e * CB + b) * HID;
    u16x8 s0 = *(const u16x8*)(p + l * 8);
    u16x8 s1 = *(const u16x8*)(p + 512 + l * 8);
    float v[16];
    #pragma unroll
    for (int j = 0; j < 8; ++j) { v[j] = bf2f(s0[j]); v[8 + j] = bf2f(s1[j]); }
    float sum = 0.f, sq = 0.f;
    #pragma unroll
    for (int j = 0; j < 16; ++j) { sum += v[j]; sq += v[j] * v[j]; }
    #pragma unroll
    for (int m = 1; m < 64; m <<= 1) {
      sum += __shfl_xor(sum, m);
      sq  += __shfl_xor(sq, m);
    }
    const float mu  = sum * (1.0f / HID);
    const float var = sq * (1.0f / HID) - mu * mu;
    const float rs  = rsqrtf(var + LN_EPS);
    const float* gp = g  + (size_t)e * HID;
    const float* bp = be + (size_t)e * HID;
    const float* w  = W3 + (size_t)e * HID;
    float dot = 0.f;
    #pragma unroll
    for (int j = 0; j < 8; ++j) {
      const int c0 = l * 8 + j, c1 = 512 + l * 8 + j;
      float x0 = fmaxf((v[j]     - mu) * rs * gp[c0] + bp[c0], 0.f);
      float x1 = fmaxf((v[8 + j] - mu) * rs * gp[c1] + bp[c1], 0.f);
      dot += x0 * w[c0] + x1 * w[c1];
    }
    #pragma unroll
    for (int m = 1; m < 64; m <<= 1) dot += __shfl_xor(dot, m);
    if (l == 0) {
      const float qe = dot + b3[e];
      qsh[e] = qe;
      out[BATCH + (size_t)e * BATCH + b0 + b] = qe;   // qs
    }
  }
  __syncthreads();
  if (threadIdx.x == 0) {
    float m = qsh[0];
    #pragma unroll
    for (int i = 1; i < EN; ++i) m = fminf(m, qsh[i]);
    out[b0 + b] = m;                                   // q
  }
}

extern "C" void kernel_launch(void* const* d_in, const int* in_sizes, int n_in,
                              void* d_out, int out_size, void* d_ws, size_t ws_size,
                              hipStream_t stream) {
  const float* x   = (const float*)d_in[0];
  const float* W1  = (const float*)d_in[1];
  const float* b1  = (const float*)d_in[2];
  const float* g1  = (const float*)d_in[3];
  const float* be1 = (const float*)d_in[4];
  const float* W2  = (const float*)d_in[5];
  const float* b2  = (const float*)d_in[6];
  const float* g2  = (const float*)d_in[7];
  const float* be2 = (const float*)d_in[8];
  const float* W3  = (const float*)d_in[9];
  const float* b3  = (const float*)d_in[10];
  float* out = (float*)d_out;

  // ---- fixed workspace region: converted inputs (40 MB) ----
  char* ws = (char*)d_ws;
  uint16_t* xb  = (uint16_t*)ws; ws += (size_t)BATCH * DIN * 2;      // 16 MB
  uint16_t* w1t = (uint16_t*)ws; ws += (size_t)EN * DIN * HID * 2;   // 8 MB
  uint16_t* w2t = (uint16_t*)ws; ws += (size_t)EN * HID * HID * 2;   // 16 MB
  size_t fixed = (size_t)(ws - (char*)d_ws);

  // ---- batch-chunk size CB (power of 2, >=256) so h1+h2 fit in workspace ----
  size_t avail = (ws_size > fixed) ? (ws_size - fixed) : 0;
  const size_t per_row = 2ULL * EN * HID * 2ULL;   // h1+h2 bytes per batch row
  int CB = BATCH;
  while (CB > 256 && (size_t)CB * per_row > avail) CB >>= 1;
  const int nchunks = BATCH / CB;
  const int kshift = __builtin_ctz(CB);

  uint16_t* h1 = (uint16_t*)ws; ws += (size_t)EN * CB * HID * 2;
  uint16_t* h2 = (uint16_t*)ws;

  // ---- one-time conversions ----
  cvt_bf16<<<(BATCH * DIN / 4 + 255) / 256, 256, 0, stream>>>(x, xb, (long)BATCH * DIN);
  transpose_cvt<<<dim3(HID / 32, DIN / 32, EN), 256, 0, stream>>>(W1, w1t, DIN, HID);
  transpose_cvt<<<dim3(HID / 32, HID / 32, EN), 256, 0, stream>>>(W2, w2t, HID, HID);

  const int gblocks = (CB / 256) * (HID / 256) * EN;

  for (int c = 0; c < nchunks; ++c) {
    const int b0 = c * CB;
    gemm4w<<<gblocks, 256, 0, stream>>>(xb + (size_t)b0 * DIN, (size_t)0,
                                        w1t, b1, h1, CB, DIN);
    ln_relu<<<(EN * CB) / 4, 256, 0, stream>>>(h1, g1, be1, kshift);
    gemm4w<<<gblocks, 256, 0, stream>>>(h1, (size_t)CB * HID,
                                        w2t, b2, h2, CB, HID);
    ln_head<<<CB, 256, 0, stream>>>(h2, g2, be2, W3, b3, out, b0, CB);
  }
}

// Round 17
// 659.495 us; speedup vs baseline: 1.2282x; 1.0183x over previous
//
#include <hip/hip_runtime.h>
#include <hip/hip_bf16.h>
#include <stdint.h>

#define EN    8
#define DIN   512
#define HID   1024
#define BATCH 16384
#define LN_EPS 1e-5f

typedef __bf16   bf16x8 __attribute__((ext_vector_type(8)));
typedef float    f32x4  __attribute__((ext_vector_type(4)));
typedef uint16_t u16x8  __attribute__((ext_vector_type(8)));
typedef uint16_t u16x4  __attribute__((ext_vector_type(4)));
typedef float    fl4    __attribute__((ext_vector_type(4)));

__device__ __forceinline__ uint16_t f2bf(float f) {
  uint32_t x = __builtin_bit_cast(uint32_t, f);
  uint32_t r = (x + 0x7fffu + ((x >> 16) & 1u)) >> 16;  // RNE
  return (uint16_t)r;
}
__device__ __forceinline__ float bf2f(uint16_t u) {
  return __builtin_bit_cast(float, (uint32_t)u << 16);
}

__device__ __forceinline__ void gload16(const uint16_t* g, char* lds_d) {
  __builtin_amdgcn_global_load_lds(
      (const __attribute__((address_space(1))) uint32_t*)g,
      (__attribute__((address_space(3))) uint32_t*)lds_d, 16, 0, 0);
}

__device__ __forceinline__ f32x4 MF(bf16x8 a, bf16x8 b, f32x4 c) {
  return __builtin_amdgcn_mfma_f32_16x16x32_bf16(a, b, c, 0, 0, 0);
}

#define SB0() __builtin_amdgcn_sched_barrier(0)

// ---------------- conversion: fp32 -> bf16 ----------------
__global__ __launch_bounds__(256) void cvt_bf16(const float* __restrict__ src,
                                                uint16_t* __restrict__ dst, long n) {
  long i = ((long)blockIdx.x * 256 + threadIdx.x) * 4;
  if (i >= n) return;
  fl4 v = *(const fl4*)(src + i);
  u16x4 o;
  #pragma unroll
  for (int j = 0; j < 4; ++j) o[j] = f2bf(v[j]);
  *(u16x4*)(dst + i) = o;
}

// ---------------- transpose + convert: [E][R][C] fp32 -> [E][C][R] bf16 ----------------
__global__ __launch_bounds__(256) void transpose_cvt(const float* __restrict__ src,
                                                     uint16_t* __restrict__ dst,
                                                     int R, int C) {
  __shared__ float tile[32][33];
  const int e = blockIdx.z;
  const int c0 = blockIdx.x * 32;
  const int r0 = blockIdx.y * 32;
  const int tx = threadIdx.x & 31, ty = threadIdx.x >> 5;
  const float* s = src + (size_t)e * R * C;
  uint16_t*    d = dst + (size_t)e * R * C;
  #pragma unroll
  for (int i = 0; i < 32; i += 8)
    tile[ty + i][tx] = s[(size_t)(r0 + ty + i) * C + (c0 + tx)];
  __syncthreads();
  #pragma unroll
  for (int i = 0; i < 32; i += 8)
    d[(size_t)(c0 + ty + i) * R + (r0 + tx)] = f2bf(tile[tx][ty + i]);
}

// ====== 256x256 GEMM, 4 waves, 128x128 wave tile, register-dbuf fragments ======
// C[e][M][HID] = A[e][M][K] * Bt[e][HID][K]^T + bias.  256 thr = 4 waves (2M x 2N).
// BK=64.  LDS 128 KiB = 2 dbuf x (A 256x128B + B 256x128B).  128B rows, 16B unit u
// at phys u ^ (row&7) (proven 0-conflict).  Empirical best of 9 structural
// variants (R3-R16): 77us/dispatch, total 659.6us (R14).
__global__ __launch_bounds__(256, 1) void gemm4w(
    const uint16_t* __restrict__ A, size_t a_estride,
    const uint16_t* __restrict__ Bt,
    const float*    __restrict__ bias,
    uint16_t*       __restrict__ C,
    int M, int K) {
  __shared__ __attribute__((aligned(16))) char lds[131072];
  const int tid = threadIdx.x;
  const int bx  = blockIdx.x;
  const int e   = bx & 7;            // member -> XCD pinning
  const int t   = bx >> 3;
  const int mt  = t >> 2;            // nt inner: neighbors share A panel
  const int nt  = t & 3;
  const int NT  = K >> 6;            // K-tiles of 64

  const uint16_t* Ae = A + (size_t)e * a_estride + (size_t)(mt * 256) * K;
  const uint16_t* Be = Bt + ((size_t)e * HID + nt * 256) * K;

  const int l  = tid & 63, wid = tid >> 6;
  const int wr = wid >> 1, wc = wid & 1;        // 2 x 2 waves, tile 128x128
  const int fr = l & 15, kq = l >> 4, f7 = fr & 7;

  // staging: lane covers row (wid*8 + l>>3) (+j*32), phys unit l&7, logical su
  const int r8 = l >> 3;
  const int su = (l & 7) ^ r8;
  const uint16_t* pA = Ae + (size_t)(wid * 8 + r8) * K + su * 8;
  const uint16_t* pB = Be + (size_t)(wid * 8 + r8) * K + su * 8;
  char* const dst0 = lds + tid * 16;

  // frag read byte offsets (within dbuf): +mi*2048; kh1 = ^64
  const int rdA0 = (wr * 128 + fr) * 128 + ((kq ^ f7) << 4);
  const int rdB0 = 32768 + (wc * 128 + fr) * 128 + ((kq ^ f7) << 4);

  f32x4 acc[8][8];
  #pragma unroll
  for (int i = 0; i < 8; ++i)
    #pragma unroll
    for (int j = 0; j < 8; ++j) acc[i][j] = (f32x4)0.0f;

  auto STAGE = [&](int kt) {
    char* db = dst0 + ((kt & 1) << 16);
    const uint16_t* sa = pA + kt * 64;
    const uint16_t* sb = pB + kt * 64;
    #pragma unroll
    for (int j = 0; j < 8; ++j) gload16(sa + (size_t)(j * 32) * K, db + j * 4096);
    #pragma unroll
    for (int j = 0; j < 8; ++j) gload16(sb + (size_t)(j * 32) * K, db + 32768 + j * 4096);
  };

  // prologue
  STAGE(0);
  asm volatile("s_waitcnt vmcnt(0)");
  SB0();
  __builtin_amdgcn_s_barrier();
  SB0();

  bf16x8 a0[8], b0[8], a1[8], b1[8];
  {
    const char* rb = lds;
    #pragma unroll
    for (int i = 0; i < 8; ++i) {
      a0[i] = *(const bf16x8*)(rb + rdA0 + i * 2048);
      b0[i] = *(const bf16x8*)(rb + rdB0 + i * 2048);
    }
  }

  for (int kt = 0; kt < NT; ++kt) {
    const char* rb = lds + ((kt & 1) << 16);
    const char* rq = lds + (((kt + 1) & 1) << 16);
    if (kt + 1 < NT) STAGE(kt + 1);            // 16 gload_lds, lands during this kt
    // ---- kh0: 64 MFMA; kh1 frag reads issued ahead of each burst ----
    #pragma unroll
    for (int mi = 0; mi < 8; ++mi) {
      a1[mi] = *(const bf16x8*)(rb + ((rdA0 + mi * 2048) ^ 64));
      b1[mi] = *(const bf16x8*)(rb + ((rdB0 + mi * 2048) ^ 64));
      __builtin_amdgcn_s_setprio(1);
      #pragma unroll
      for (int ni = 0; ni < 8; ++ni)
        acc[mi][ni] = MF(a0[mi], b0[ni], acc[mi][ni]);
      __builtin_amdgcn_s_setprio(0);
    }
    // ---- kh1: 64 MFMA ----
    #pragma unroll
    for (int mi = 0; mi < 8; ++mi) {
      __builtin_amdgcn_s_setprio(1);
      #pragma unroll
      for (int ni = 0; ni < 8; ++ni)
        acc[mi][ni] = MF(a1[mi], b1[ni], acc[mi][ni]);
      __builtin_amdgcn_s_setprio(0);
    }
    if (kt + 1 < NT) {
      asm volatile("s_waitcnt vmcnt(0)");       // stage(kt+1) landed (issued ~2500 cyc ago)
      SB0();
      __builtin_amdgcn_s_barrier();             // publish to all waves; WAR separation
      SB0();
      #pragma unroll
      for (int i = 0; i < 8; ++i) {             // next tile kh0 frags
        a0[i] = *(const bf16x8*)(rq + rdA0 + i * 2048);
        b0[i] = *(const bf16x8*)(rq + rdB0 + i * 2048);
      }
    }
  }

  // epilogue: bias + direct bf16 store.  D map: col=l&15, row=(l>>4)*4+i [m89]
  const int col0 = nt * 256 + wc * 128 + fr;
  const int row0 = mt * 256 + wr * 128 + kq * 4;
  float bv[8];
  #pragma unroll
  for (int ni = 0; ni < 8; ++ni) bv[ni] = bias[(size_t)e * HID + col0 + ni * 16];
  #pragma unroll
  for (int mi = 0; mi < 8; ++mi) {
    #pragma unroll
    for (int i = 0; i < 4; ++i) {
      const int rg = row0 + mi * 16 + i;
      uint16_t* cp = C + ((size_t)e * M + rg) * HID + col0;
      #pragma unroll
      for (int ni = 0; ni < 8; ++ni)
        cp[ni * 16] = f2bf(acc[mi][ni][i] + bv[ni]);
    }
  }
}

// ---------------- LayerNorm + ReLU, in place on bf16 [E*CB][HID] ----------------
__global__ __launch_bounds__(256) void ln_relu(uint16_t* __restrict__ h,
                                               const float* __restrict__ g,
                                               const float* __restrict__ be,
                                               int kshift) {        // e = row >> kshift
  const int wid = threadIdx.x >> 6, l = threadIdx.x & 63;
  const long row = (long)blockIdx.x * 4 + wid;
  const int e = (int)(row >> kshift);
  uint16_t* p = h + row * HID;

  u16x8 s0 = *(const u16x8*)(p + l * 8);
  u16x8 s1 = *(const u16x8*)(p + 512 + l * 8);
  float v[16];
  #pragma unroll
  for (int j = 0; j < 8; ++j) { v[j] = bf2f(s0[j]); v[8 + j] = bf2f(s1[j]); }

  float sum = 0.f, sq = 0.f;
  #pragma unroll
  for (int j = 0; j < 16; ++j) { sum += v[j]; sq += v[j] * v[j]; }
  #pragma unroll
  for (int m = 1; m < 64; m <<= 1) {
    sum += __shfl_xor(sum, m);
    sq  += __shfl_xor(sq, m);
  }
  const float mu  = sum * (1.0f / HID);
  const float var = sq * (1.0f / HID) - mu * mu;
  const float rs  = rsqrtf(var + LN_EPS);

  const float* gp = g  + (size_t)e * HID;
  const float* bp = be + (size_t)e * HID;
  u16x8 o0, o1;
  #pragma unroll
  for (int j = 0; j < 8; ++j) {
    const int c0 = l * 8 + j, c1 = 512 + l * 8 + j;
    float x0 = (v[j]     - mu) * rs * gp[c0] + bp[c0];
    float x1 = (v[8 + j] - mu) * rs * gp[c1] + bp[c1];
    o0[j] = f2bf(fmaxf(x0, 0.f));
    o1[j] = f2bf(fmaxf(x1, 0.f));
  }
  *(u16x8*)(p + l * 8) = o0;
  *(u16x8*)(p + 512 + l * 8) = o1;
}

// ------- fused LN2 + ReLU + head dot + min: reads pre-LN h2, writes q/qs only -------
__global__ __launch_bounds__(256) void ln_head(const uint16_t* __restrict__ h,
                                               const float* __restrict__ g,
                                               const float* __restrict__ be,
                                               const float* __restrict__ W3,
                                               const float* __restrict__ b3,
                                               float* __restrict__ out,
                                               int b0, int CB) {
  __shared__ float qsh[EN];
  const int wv = threadIdx.x >> 6, l = threadIdx.x & 63;
  const long b = blockIdx.x;
  #pragma unroll
  for (int ee = 0; ee < 2; ++ee) {
    const int e = wv + ee * 4;
    const uint16_t* p = h + ((size_t)e * CB + b) * HID;
    u16x8 s0 = *(const u16x8*)(p + l * 8);
    u16x8 s1 = *(const u16x8*)(p + 512 + l * 8);
    float v[16];
    #pragma unroll
    for (int j = 0; j < 8; ++j) { v[j] = bf2f(s0[j]); v[8 + j] = bf2f(s1[j]); }
    float sum = 0.f, sq = 0.f;
    #pragma unroll
    for (int j = 0; j < 16; ++j) { sum += v[j]; sq += v[j] * v[j]; }
    #pragma unroll
    for (int m = 1; m < 64; m <<= 1) {
      sum += __shfl_xor(sum, m);
      sq  += __shfl_xor(sq, m);
    }
    const float mu  = sum * (1.0f / HID);
    const float var = sq * (1.0f / HID) - mu * mu;
    const float rs  = rsqrtf(var + LN_EPS);
    const float* gp = g  + (size_t)e * HID;
    const float* bp = be + (size_t)e * HID;
    const float* w  = W3 + (size_t)e * HID;
    float dot = 0.f;
    #pragma unroll
    for (int j = 0; j < 8; ++j) {
      const int c0 = l * 8 + j, c1 = 512 + l * 8 + j;
      float x0 = fmaxf((v[j]     - mu) * rs * gp[c0] + bp[c0], 0.f);
      float x1 = fmaxf((v[8 + j] - mu) * rs * gp[c1] + bp[c1], 0.f);
      dot += x0 * w[c0] + x1 * w[c1];
    }
    #pragma unroll
    for (int m = 1; m < 64; m <<= 1) dot += __shfl_xor(dot, m);
    if (l == 0) {
      const float qe = dot + b3[e];
      qsh[e] = qe;
      out[BATCH + (size_t)e * BATCH + b0 + b] = qe;   // qs
    }
  }
  __syncthreads();
  if (threadIdx.x == 0) {
    float m = qsh[0];
    #pragma unroll
    for (int i = 1; i < EN; ++i) m = fminf(m, qsh[i]);
    out[b0 + b] = m;                                   // q
  }
}

extern "C" void kernel_launch(void* const* d_in, const int* in_sizes, int n_in,
                              void* d_out, int out_size, void* d_ws, size_t ws_size,
                              hipStream_t stream) {
  const float* x   = (const float*)d_in[0];
  const float* W1  = (const float*)d_in[1];
  const float* b1  = (const float*)d_in[2];
  const float* g1  = (const float*)d_in[3];
  const float* be1 = (const float*)d_in[4];
  const float* W2  = (const float*)d_in[5];
  const float* b2  = (const float*)d_in[6];
  const float* g2  = (const float*)d_in[7];
  const float* be2 = (const float*)d_in[8];
  const float* W3  = (const float*)d_in[9];
  const float* b3  = (const float*)d_in[10];
  float* out = (float*)d_out;

  // ---- fixed workspace region: converted inputs (40 MB) ----
  char* ws = (char*)d_ws;
  uint16_t* xb  = (uint16_t*)ws; ws += (size_t)BATCH * DIN * 2;      // 16 MB
  uint16_t* w1t = (uint16_t*)ws; ws += (size_t)EN * DIN * HID * 2;   // 8 MB
  uint16_t* w2t = (uint16_t*)ws; ws += (size_t)EN * HID * HID * 2;   // 16 MB
  size_t fixed = (size_t)(ws - (char*)d_ws);

  // ---- batch-chunk size CB (power of 2, >=256) so h1+h2 fit in workspace ----
  size_t avail = (ws_size > fixed) ? (ws_size - fixed) : 0;
  const size_t per_row = 2ULL * EN * HID * 2ULL;   // h1+h2 bytes per batch row
  int CB = BATCH;
  while (CB > 256 && (size_t)CB * per_row > avail) CB >>= 1;
  const int nchunks = BATCH / CB;
  const int kshift = __builtin_ctz(CB);

  uint16_t* h1 = (uint16_t*)ws; ws += (size_t)EN * CB * HID * 2;
  uint16_t* h2 = (uint16_t*)ws;

  // ---- one-time conversions ----
  cvt_bf16<<<(BATCH * DIN / 4 + 255) / 256, 256, 0, stream>>>(x, xb, (long)BATCH * DIN);
  transpose_cvt<<<dim3(HID / 32, DIN / 32, EN), 256, 0, stream>>>(W1, w1t, DIN, HID);
  transpose_cvt<<<dim3(HID / 32, HID / 32, EN), 256, 0, stream>>>(W2, w2t, HID, HID);

  const int gblocks = (CB / 256) * (HID / 256) * EN;

  for (int c = 0; c < nchunks; ++c) {
    const int b0 = c * CB;
    gemm4w<<<gblocks, 256, 0, stream>>>(xb + (size_t)b0 * DIN, (size_t)0,
                                        w1t, b1, h1, CB, DIN);
    ln_relu<<<(EN * CB) / 4, 256, 0, stream>>>(h1, g1, be1, kshift);
    gemm4w<<<gblocks, 256, 0, stream>>>(h1, (size_t)CB * HID,
                                        w2t, b2, h2, CB, HID);
    ln_head<<<CB, 256, 0, stream>>>(h2, g2, be2, W3, b3, out, b0, CB);
  }
}